// Round 2
// baseline (20053.450 us; speedup 1.0000x reference)
//
#include <hip/hip_runtime.h>
#include <hip/hip_bf16.h>

#define BB   1024
#define TT   64
#define IND  64
#define HH   512
#define G4   2048   // 4*H
#define NLAYER 8
#define NCLS 128
#define KP   1024   // packed W k-stride (layer0 uses first 576 cols)

typedef __bf16 bf16x8 __attribute__((ext_vector_type(8)));
typedef float  f32x4  __attribute__((ext_vector_type(4)));

typedef const __attribute__((address_space(1))) void* as1cvp;
typedef __attribute__((address_space(3))) void* as3vp;

__device__ __forceinline__ void gload16(void* lds, const void* g) {
  __builtin_amdgcn_global_load_lds((as1cvp)g, (as3vp)lds, 16, 0, 0);
}

__device__ __forceinline__ float sigmf(float x) { return 1.f / (1.f + __expf(-x)); }

// ---------------- prep kernels ----------------
__global__ void cvt_kernel(const float* __restrict__ s, __bf16* __restrict__ d, int n) {
  int i = blockIdx.x * 256 + threadIdx.x;
  if (i < n) d[i] = (__bf16)s[i];
}

// Pack W[l][n][k]: k<512 -> Whh rows; k>=512 -> Wih rows (layer0: 64 wide, rest 0)
__global__ void pack_w(const float* __restrict__ whh0, const float* __restrict__ wih0,
                       const float* __restrict__ whh, const float* __restrict__ wih,
                       __bf16* __restrict__ Wp) {
  int i = blockIdx.x * 256 + threadIdx.x;  // 8*2048*1024
  int k = i & (KP - 1), n = (i >> 10) & 2047, l = i >> 21;
  float v;
  if (k < 512) v = (l == 0) ? whh0[n * 512 + k] : whh[((size_t)(l - 1) * G4 + n) * 512 + k];
  else if (l == 0) v = (k < 512 + IND) ? wih0[n * IND + (k - 512)] : 0.f;
  else v = wih[((size_t)(l - 1) * G4 + n) * 512 + (k - 512)];
  Wp[i] = (__bf16)v;
}

__global__ void bias_prep(const float* __restrict__ bi0, const float* __restrict__ bh0,
                          const float* __restrict__ bi, const float* __restrict__ bh,
                          float* __restrict__ biasb) {
  int i = blockIdx.x * 256 + threadIdx.x;  // 8*2048
  int l = i >> 11, k = i & 2047;
  float v = (l == 0) ? (bi0[k] + bh0[k]) : (bi[(l - 1) * G4 + k] + bh[(l - 1) * G4 + k]);
  biasb[i] = v;
}

__global__ void xpose(const float* __restrict__ x, __bf16* __restrict__ xin) {
  int i = blockIdx.x * 256 + threadIdx.x;  // B*T*64
  int ii = i & 63;
  int t = (i >> 6) & 63;
  int b = i >> 12;
  xin[((size_t)t * BB + b) * IND + ii] = (__bf16)x[i];
}

__global__ void zero_bf16(__bf16* __restrict__ p, int n) {
  int i = blockIdx.x * 256 + threadIdx.x;
  if (i < n) p[i] = (__bf16)0.f;
}

__global__ void zero_u32(unsigned* __restrict__ p, int n) {
  int i = blockIdx.x * 256 + threadIdx.x;
  if (i < n) p[i] = 0u;
}

// ---------------- persistent fused LSTM layer ----------------
// grid 256 (1 block/CU), block 256. Block (bx,by): rows b0..b0+63,
// cols = 4 gates x 32 j  (j0 = by*32). Col map: j-frag jf -> gate=jf&3,
// jj-half=jf>>2, so each wave holds all 4 gates for its (row,jj) cells.
// K-loop: register-direct 16B fragment loads, NO LDS, NO barriers.
// Timestep sync: per-bx-group monotone counter, release-add / relaxed-spin.
template <int NKX>
__global__ __launch_bounds__(256, 1) void layer_kernel(
    const __bf16* __restrict__ xseq, const int xstr,
    __bf16* __restrict__ Hout,
    const __bf16* __restrict__ Wp,      // [2048][KP]
    const float* __restrict__ bias,     // [2048]
    const __bf16* __restrict__ hzero,   // [B][512] zeros
    unsigned* __restrict__ cnt) {       // [16] this layer's counters
  const int id = blockIdx.x;
  // XCD swizzle: XCD = id%8 hosts by in {2a, 2a+1} -> W slice stays in its L2
  const int bx = (id >> 3) & 15;
  const int by = ((id & 7) << 1) | (id >> 7);
  const int b0 = bx << 6, j0 = by << 5;
  const int tid = threadIdx.x;
  const int lane = tid & 63, wv = tid >> 6;
  const int qr = lane >> 4, ml = lane & 15;
  const int wr = (wv >> 1) << 5;   // {0,32} row-half
  const int sub = (wv & 1) << 4;   // {0,16} jj-half

  const __bf16* wb[4];
  float bv[4];
#pragma unroll
  for (int g = 0; g < 4; ++g) {
    const int n = g * 512 + j0 + sub + ml;
    wb[g] = Wp + (size_t)n * KP + qr * 8;
    bv[g] = bias[n];
  }
  const int rowA0 = b0 + wr + ml;
  const int rowA1 = rowA0 + 16;
  const int rb = b0 + wr + (qr << 2);
  const int jcol = j0 + sub + ml;
  float c8[2][4] = {{0.f, 0.f, 0.f, 0.f}, {0.f, 0.f, 0.f, 0.f}};

  for (int t = 0; t < TT; ++t) {
    const __bf16* hp;
    if (t == 0) {
      hp = hzero;
    } else {
      const unsigned tgt = (unsigned)(t << 4);
      unsigned v = __hip_atomic_load(cnt + bx, __ATOMIC_RELAXED, __HIP_MEMORY_SCOPE_AGENT);
      while (v < tgt) {
        __builtin_amdgcn_s_sleep(2);
        v = __hip_atomic_load(cnt + bx, __ATOMIC_RELAXED, __HIP_MEMORY_SCOPE_AGENT);
      }
      // (v>>20)==0 at runtime; data-dependence stops hoisting of hp loads
      // above the spin without paying buffer_inv per poll (addresses are
      // fresh-per-step, so no stale-cache hazard; LLC is fresh post-release).
      hp = Hout + (size_t)(t - 1) * BB * HH + (v >> 20);
    }
    const __bf16* a0 = hp + (size_t)rowA0 * HH + qr * 8;
    const __bf16* a1 = hp + (size_t)rowA1 * HH + qr * 8;
    const __bf16* x0 = xseq + ((size_t)t * BB + rowA0) * xstr + qr * 8;
    const __bf16* x1 = xseq + ((size_t)t * BB + rowA1) * xstr + qr * 8;

    f32x4 acc[2][4];
#pragma unroll
    for (int g = 0; g < 4; ++g)
#pragma unroll
      for (int r = 0; r < 4; ++r) {
        acc[0][g][r] = bv[g];
        acc[1][g][r] = bv[g];
      }

#pragma unroll
    for (int kt = 0; kt < 16; ++kt) {  // h-part, K=512
      const bf16x8 af0 = *(const bf16x8*)(a0 + kt * 32);
      const bf16x8 af1 = *(const bf16x8*)(a1 + kt * 32);
#pragma unroll
      for (int g = 0; g < 4; ++g) {
        const bf16x8 wf = *(const bf16x8*)(wb[g] + kt * 32);
        acc[0][g] = __builtin_amdgcn_mfma_f32_16x16x32_bf16(af0, wf, acc[0][g], 0, 0, 0);
        acc[1][g] = __builtin_amdgcn_mfma_f32_16x16x32_bf16(af1, wf, acc[1][g], 0, 0, 0);
      }
    }
#pragma unroll
    for (int kt = 0; kt < NKX; ++kt) {  // x-part, K = NKX*32
      const bf16x8 af0 = *(const bf16x8*)(x0 + kt * 32);
      const bf16x8 af1 = *(const bf16x8*)(x1 + kt * 32);
#pragma unroll
      for (int g = 0; g < 4; ++g) {
        const bf16x8 wf = *(const bf16x8*)(wb[g] + (16 + kt) * 32);
        acc[0][g] = __builtin_amdgcn_mfma_f32_16x16x32_bf16(af0, wf, acc[0][g], 0, 0, 0);
        acc[1][g] = __builtin_amdgcn_mfma_f32_16x16x32_bf16(af1, wf, acc[1][g], 0, 0, 0);
      }
    }

    __bf16* ho = Hout + (size_t)t * BB * HH;
#pragma unroll
    for (int i = 0; i < 2; ++i)
#pragma unroll
      for (int r = 0; r < 4; ++r) {
        const float gi = sigmf(acc[i][0][r]);
        const float gf = sigmf(acc[i][1][r]);
        const float gg = tanhf(acc[i][2][r]);
        const float go = sigmf(acc[i][3][r]);
        const float cv = gf * c8[i][r] + gi * gg;
        c8[i][r] = cv;
        ho[(size_t)(rb + i * 16 + r) * HH + jcol] = (__bf16)(go * tanhf(cv));
      }
    __syncthreads();  // drain all waves' h-stores (vmcnt(0)) before release
    if (tid == 0)
      __hip_atomic_fetch_add(cnt + bx, 1u, __ATOMIC_RELEASE, __HIP_MEMORY_SCOPE_AGENT);
  }
}

// ---------------- FC (bf16 MFMA, K-split) ----------------
__global__ __launch_bounds__(256, 2) void fc_kernel(
    const __bf16* __restrict__ hseq, const __bf16* __restrict__ fcw,
    float* __restrict__ partial) {
  __shared__ __bf16 At[64 * 32];
  __shared__ __bf16 Wt[128 * 32];
  const int tid = threadIdx.x;
  const int b0 = blockIdx.x * 64;
  const int kbase = blockIdx.y * 2048;
  const int lane = tid & 63, wv = tid >> 6;
  const int qr = lane >> 4, ml = lane & 15;
  const int wr = (wv >> 1) * 32, wc = (wv & 1) * 64;
  const int sr = tid >> 2, sk = (tid & 3) * 8;

  f32x4 acc[2][4];
  for (int i = 0; i < 2; i++)
    for (int j = 0; j < 4; j++)
      for (int r = 0; r < 4; r++) acc[i][j][r] = 0.f;

  for (int kt = 0; kt < 64; ++kt) {
    const int k = kbase + kt * 32;
    const int t = k >> 9;
    const int jb = k & 511;
    gload16(&At[tid * 8],        hseq + ((size_t)t * BB + b0 + sr) * HH + jb + sk);
    gload16(&Wt[tid * 8],        fcw + (size_t)sr * (TT * HH) + k + sk);
    gload16(&Wt[2048 + tid * 8], fcw + (size_t)(sr + 64) * (TT * HH) + k + sk);
    __syncthreads();
    bf16x8 af[2], bfr[4];
    for (int i = 0; i < 2; i++) af[i]  = *(const bf16x8*)&At[(wr + i * 16 + ml) * 32 + qr * 8];
    for (int j = 0; j < 4; j++) bfr[j] = *(const bf16x8*)&Wt[(wc + j * 16 + ml) * 32 + qr * 8];
    for (int i = 0; i < 2; i++)
      for (int j = 0; j < 4; j++)
        acc[i][j] = __builtin_amdgcn_mfma_f32_16x16x32_bf16(af[i], bfr[j], acc[i][j], 0, 0, 0);
    __syncthreads();
  }
  for (int i = 0; i < 2; i++)
    for (int j = 0; j < 4; j++)
      for (int r = 0; r < 4; r++)
        partial[((size_t)blockIdx.y * BB + b0 + wr + i * 16 + qr * 4 + r) * NCLS + wc + j * 16 + ml] =
            acc[i][j][r];
}

__global__ void fc_reduce(const float* __restrict__ partial, const float* __restrict__ fcb,
                          float* __restrict__ out) {
  int i = blockIdx.x * 256 + threadIdx.x;  // B*128
  float s = fcb[i & 127];
  for (int p = 0; p < 16; p++) s += partial[(size_t)p * (BB * NCLS) + i];
  out[i] = s;
}

// ---------------- host ----------------
extern "C" void kernel_launch(void* const* d_in, const int* in_sizes, int n_in,
                              void* d_out, int out_size, void* d_ws, size_t ws_size,
                              hipStream_t stream) {
  const float* x    = (const float*)d_in[0];
  const float* wih0 = (const float*)d_in[1];
  const float* whh0 = (const float*)d_in[2];
  const float* bih0 = (const float*)d_in[3];
  const float* bhh0 = (const float*)d_in[4];
  const float* wih  = (const float*)d_in[5];
  const float* whh  = (const float*)d_in[6];
  const float* bih  = (const float*)d_in[7];
  const float* bhh  = (const float*)d_in[8];
  const float* fcw  = (const float*)d_in[9];
  const float* fcb  = (const float*)d_in[10];
  float* out = (float*)d_out;

  size_t off = 0;
  char* base = (char*)d_ws;
  auto carve = [&](size_t bytes) -> char* {
    char* p = base + off;
    off += (bytes + 255) & ~(size_t)255;
    return p;
  };
  __bf16*   xin   = (__bf16*)carve((size_t)TT * BB * IND * 2);
  __bf16*   Wp    = (__bf16*)carve((size_t)NLAYER * G4 * KP * 2);
  __bf16*   fcwb  = (__bf16*)carve((size_t)NCLS * TT * HH * 2);
  float*    biasb = (float*)carve((size_t)NLAYER * G4 * 4);
  __bf16*   hseqA = (__bf16*)carve((size_t)TT * BB * HH * 2);
  __bf16*   hseqB = (__bf16*)carve((size_t)TT * BB * HH * 2);
  __bf16*   hzero = (__bf16*)carve((size_t)BB * HH * 2);
  float*    part  = (float*)carve((size_t)16 * BB * NCLS * 4);
  unsigned* cnt   = (unsigned*)carve((size_t)NLAYER * 16 * 4);

  // prep
  pack_w<<<(NLAYER * G4 * KP) / 256, 256, 0, stream>>>(whh0, wih0, whh, wih, Wp);
  cvt_kernel<<<(NCLS * TT * HH) / 256, 256, 0, stream>>>(fcw, fcwb, NCLS * TT * HH);
  bias_prep<<<(NLAYER * G4) / 256, 256, 0, stream>>>(bih0, bhh0, bih, bhh, biasb);
  xpose<<<(TT * BB * IND) / 256, 256, 0, stream>>>(x, xin);
  zero_bf16<<<(BB * HH) / 256, 256, 0, stream>>>(hzero, BB * HH);
  zero_u32<<<1, 256, 0, stream>>>(cnt, NLAYER * 16);

  for (int l = 0; l < NLAYER; ++l) {
    const __bf16* xs = (l == 0) ? xin : ((l & 1) ? hseqA : hseqB);
    __bf16* Ho = (l & 1) ? hseqB : hseqA;
    const __bf16* Wl = Wp + (size_t)l * G4 * KP;
    const float* bl = biasb + l * G4;
    unsigned* cl = cnt + l * 16;
    if (l == 0)
      layer_kernel<2><<<256, 256, 0, stream>>>(xs, IND, Ho, Wl, bl, hzero, cl);
    else
      layer_kernel<16><<<256, 256, 0, stream>>>(xs, HH, Ho, Wl, bl, hzero, cl);
  }
  const __bf16* hfinal = hseqB;  // layer 7 writes hseqB
  fc_kernel<<<dim3(16, 16), 256, 0, stream>>>(hfinal, fcwb, part);
  fc_reduce<<<(BB * NCLS) / 256, 256, 0, stream>>>(part, fcb, out);
}

// Round 3
// 17750.526 us; speedup vs baseline: 1.1297x; 1.1297x over previous
//
#include <hip/hip_runtime.h>
#include <hip/hip_bf16.h>

#define BB   1024
#define TT   64
#define IND  64
#define HH   512
#define G4   2048   // 4*H
#define NLAYER 8
#define NCLS 128
#define KP   1024   // packed W k-stride: k<512 = W_hh, k>=512 = W_ih (layer0 64 + pad)

typedef __bf16 bf16x8 __attribute__((ext_vector_type(8)));
typedef float  f32x4  __attribute__((ext_vector_type(4)));

typedef const __attribute__((address_space(1))) void* as1cvp;
typedef __attribute__((address_space(3))) void* as3vp;

__device__ __forceinline__ void gload16(void* lds, const void* g) {
  __builtin_amdgcn_global_load_lds((as1cvp)g, (as3vp)lds, 16, 0, 0);
}

__device__ __forceinline__ float sigmf(float x) { return 1.f / (1.f + __expf(-x)); }
__device__ __forceinline__ float tanhfast(float x) { return 2.f / (1.f + __expf(-2.f * x)) - 1.f; }

// ---------------- prep kernels ----------------
__global__ void cvt_kernel(const float* __restrict__ s, __bf16* __restrict__ d, int n) {
  int i = blockIdx.x * 256 + threadIdx.x;
  if (i < n) d[i] = (__bf16)s[i];
}

__global__ void pack_w(const float* __restrict__ whh0, const float* __restrict__ wih0,
                       const float* __restrict__ whh, const float* __restrict__ wih,
                       __bf16* __restrict__ Wp) {
  int i = blockIdx.x * 256 + threadIdx.x;  // 8*2048*1024
  int k = i & (KP - 1), n = (i >> 10) & 2047, l = i >> 21;
  float v;
  if (k < 512) v = (l == 0) ? whh0[n * 512 + k] : whh[((size_t)(l - 1) * G4 + n) * 512 + k];
  else if (l == 0) v = (k < 512 + IND) ? wih0[n * IND + (k - 512)] : 0.f;
  else v = wih[((size_t)(l - 1) * G4 + n) * 512 + (k - 512)];
  Wp[i] = (__bf16)v;
}

__global__ void bias_prep(const float* __restrict__ bi0, const float* __restrict__ bh0,
                          const float* __restrict__ bi, const float* __restrict__ bh,
                          float* __restrict__ biasb) {
  int i = blockIdx.x * 256 + threadIdx.x;  // 8*2048
  int l = i >> 11, k = i & 2047;
  float v = (l == 0) ? (bi0[k] + bh0[k]) : (bi[(l - 1) * G4 + k] + bh[(l - 1) * G4 + k]);
  biasb[i] = v;
}

__global__ void xpose(const float* __restrict__ x, __bf16* __restrict__ xin) {
  int i = blockIdx.x * 256 + threadIdx.x;  // B*T*64
  int ii = i & 63;
  int t = (i >> 6) & 63;
  int b = i >> 12;
  xin[((size_t)t * BB + b) * IND + ii] = (__bf16)x[i];
}

__global__ void zero_bf16(__bf16* __restrict__ p, int n) {
  int i = blockIdx.x * 256 + threadIdx.x;
  if (i < n) p[i] = (__bf16)0.f;
}

__global__ void zero_u32(unsigned* __restrict__ p, int n) {
  int i = blockIdx.x * 256 + threadIdx.x;
  if (i < n) p[i] = 0u;
}

// ---------------- persistent fused LSTM layer ----------------
// grid 256 (1 block/CU forced by 128KB LDS), block 256.
// Block identity claimed at runtime from its XCD (s_getreg XCC_ID):
//   XCD xcc hosts bx in {bxg*8..+7} (bxg=xcc>>2), by in {byg*4..+3} (byg=xcc&3)
//   -> per-XCD static W_ih slice = 512KB, L2-resident by construction.
// W_hh tile (128 cols x 512 k = 128KB) staged to LDS ONCE, XOR-swizzled so
// fragment ds_read_b128 is <=2-way bank aliased.
// Cols = 4 gates x 32 j -> cell update register-local. c stays in registers.
// Timestep sync: per-bx monotone counter (16 releases/step), relaxed spin.
template <int NKX>
__global__ __launch_bounds__(256, 1) void layer_kernel(
    const __bf16* __restrict__ xseq, const int xstr,
    __bf16* __restrict__ Hout,
    const __bf16* __restrict__ Wl,      // this layer's packed W [2048][KP]
    const float* __restrict__ bias,     // [2048]
    const __bf16* __restrict__ hzero,   // [B][512] zeros
    unsigned* __restrict__ cnt,         // [16] per-bx counters (this layer)
    unsigned* __restrict__ xslot) {     // [8] per-XCD slot counters (this layer)
  extern __shared__ __bf16 Wlds[];      // 128KB = 16 slices x (128 rows x 32 k)
  __shared__ int sb[2];
  const int tid = threadIdx.x;

  if (tid == 0) {
    unsigned xcc;
    asm volatile("s_getreg_b32 %0, hwreg(HW_REG_XCC_ID)" : "=s"(xcc));
    xcc &= 7u;
    unsigned slot = __hip_atomic_fetch_add(xslot + xcc, 1u, __ATOMIC_RELAXED,
                                           __HIP_MEMORY_SCOPE_AGENT) & 31u;
    sb[0] = (int)(((xcc >> 2) << 3) | (slot >> 2));   // bx 0..15
    sb[1] = (int)(((xcc & 3) << 2) | (slot & 3));     // by 0..15
  }
  __syncthreads();
  const int bx = sb[0], by = sb[1];
  const int b0 = bx << 6, j0 = by << 5;

  const int lane = tid & 63, wv = tid >> 6;
  const int qr = lane >> 4, ml = lane & 15;
  const int wr = (wv >> 1) << 5;   // {0,32} row-half
  const int sub = (wv & 1) << 4;   // {0,16} j-half

  // ---- stage W_hh (k<512) into LDS, swizzled: granule g' = g ^ ((u>>1)&3)
  for (int it = 0; it < 32; ++it) {
    const int p = it * 256 + tid;           // granule 0..8191
    const int kt = p >> 9;                  // slice 0..15
    const int q = p & 511;
    const int u = q >> 2;                   // lds row 0..127
    const int g = (q & 3) ^ ((u >> 1) & 3); // source k-quad
    const int n = ((u >> 5) << 9) + j0 + (u & 31);
    gload16(&Wlds[p * 8], Wl + (size_t)n * KP + kt * 32 + g * 8);
  }

  // W_ih register-direct pointers (L2-resident via XCD affinity)
  const __bf16* wb[4];
  float bv[4];
  int wsw[4];
#pragma unroll
  for (int g = 0; g < 4; ++g) {
    const int n = g * 512 + j0 + sub + ml;
    wb[g] = Wl + (size_t)n * KP + 512 + qr * 8;
    bv[g] = bias[n];
    const int u = g * 32 + sub + ml;
    wsw[g] = u * 32 + (((qr ^ ((u >> 1) & 3))) << 3);  // lds bf16 offset, + kt*4096
  }
  const int rowA0 = b0 + wr + ml;
  const int rowA1 = rowA0 + 16;
  const int rb = b0 + wr + (qr << 2);
  const int jcol = j0 + sub + ml;
  float c8[2][4] = {{0.f, 0.f, 0.f, 0.f}, {0.f, 0.f, 0.f, 0.f}};

  __syncthreads();  // W_hh staged (waitcnt drained by barrier)

  for (int t = 0; t < TT; ++t) {
    const __bf16* hp;
    if (t == 0) {
      hp = hzero;
    } else {
      const unsigned tgt = (unsigned)(t << 4);
      unsigned v = __hip_atomic_load(cnt + bx, __ATOMIC_RELAXED, __HIP_MEMORY_SCOPE_AGENT);
      while (v < tgt) {
        __builtin_amdgcn_s_sleep(2);
        v = __hip_atomic_load(cnt + bx, __ATOMIC_RELAXED, __HIP_MEMORY_SCOPE_AGENT);
      }
      // (v>>20)==0 at runtime; data-dependence keeps hp loads after the spin.
      hp = Hout + (size_t)(t - 1) * BB * HH + (v >> 20);
    }
    const __bf16* a0 = hp + (size_t)rowA0 * HH + qr * 8;
    const __bf16* a1 = hp + (size_t)rowA1 * HH + qr * 8;
    const __bf16* x0 = xseq + ((size_t)t * BB + rowA0) * xstr + qr * 8;
    const __bf16* x1 = xseq + ((size_t)t * BB + rowA1) * xstr + qr * 8;

    f32x4 acc[2][4];
#pragma unroll
    for (int g = 0; g < 4; ++g)
#pragma unroll
      for (int r = 0; r < 4; ++r) {
        acc[0][g][r] = bv[g];
        acc[1][g][r] = bv[g];
      }

#pragma unroll
    for (int kt = 0; kt < 16; ++kt) {  // h-part: A global, W from LDS
      const bf16x8 af0 = *(const bf16x8*)(a0 + kt * 32);
      const bf16x8 af1 = *(const bf16x8*)(a1 + kt * 32);
#pragma unroll
      for (int g = 0; g < 4; ++g) {
        const bf16x8 wf = *(const bf16x8*)&Wlds[kt * 4096 + wsw[g]];
        acc[0][g] = __builtin_amdgcn_mfma_f32_16x16x32_bf16(af0, wf, acc[0][g], 0, 0, 0);
        acc[1][g] = __builtin_amdgcn_mfma_f32_16x16x32_bf16(af1, wf, acc[1][g], 0, 0, 0);
      }
    }
#pragma unroll
    for (int kt = 0; kt < NKX; ++kt) {  // x-part: A global, W_ih register-direct (L2)
      const bf16x8 af0 = *(const bf16x8*)(x0 + kt * 32);
      const bf16x8 af1 = *(const bf16x8*)(x1 + kt * 32);
#pragma unroll
      for (int g = 0; g < 4; ++g) {
        const bf16x8 wf = *(const bf16x8*)(wb[g] + kt * 32);
        acc[0][g] = __builtin_amdgcn_mfma_f32_16x16x32_bf16(af0, wf, acc[0][g], 0, 0, 0);
        acc[1][g] = __builtin_amdgcn_mfma_f32_16x16x32_bf16(af1, wf, acc[1][g], 0, 0, 0);
      }
    }

    __bf16* ho = Hout + (size_t)t * BB * HH;
#pragma unroll
    for (int i = 0; i < 2; ++i)
#pragma unroll
      for (int r = 0; r < 4; ++r) {
        const float gi = sigmf(acc[i][0][r]);
        const float gf = sigmf(acc[i][1][r]);
        const float gg = tanhfast(acc[i][2][r]);
        const float go = sigmf(acc[i][3][r]);
        const float cv = gf * c8[i][r] + gi * gg;
        c8[i][r] = cv;
        ho[(size_t)(rb + i * 16 + r) * HH + jcol] = (__bf16)(go * tanhfast(cv));
      }
    __syncthreads();  // drain stores (vmcnt(0)) before release
    if (tid == 0)
      __hip_atomic_fetch_add(cnt + bx, 1u, __ATOMIC_RELEASE, __HIP_MEMORY_SCOPE_AGENT);
  }
}

// ---------------- FC (bf16 MFMA, K-split) ----------------
__global__ __launch_bounds__(256, 2) void fc_kernel(
    const __bf16* __restrict__ hseq, const __bf16* __restrict__ fcw,
    float* __restrict__ partial) {
  __shared__ __bf16 At[64 * 32];
  __shared__ __bf16 Wt[128 * 32];
  const int tid = threadIdx.x;
  const int b0 = blockIdx.x * 64;
  const int kbase = blockIdx.y * 2048;
  const int lane = tid & 63, wv = tid >> 6;
  const int qr = lane >> 4, ml = lane & 15;
  const int wr = (wv >> 1) * 32, wc = (wv & 1) * 64;
  const int sr = tid >> 2, sk = (tid & 3) * 8;

  f32x4 acc[2][4];
  for (int i = 0; i < 2; i++)
    for (int j = 0; j < 4; j++)
      for (int r = 0; r < 4; r++) acc[i][j][r] = 0.f;

  for (int kt = 0; kt < 64; ++kt) {
    const int k = kbase + kt * 32;
    const int t = k >> 9;
    const int jb = k & 511;
    gload16(&At[tid * 8],        hseq + ((size_t)t * BB + b0 + sr) * HH + jb + sk);
    gload16(&Wt[tid * 8],        fcw + (size_t)sr * (TT * HH) + k + sk);
    gload16(&Wt[2048 + tid * 8], fcw + (size_t)(sr + 64) * (TT * HH) + k + sk);
    __syncthreads();
    bf16x8 af[2], bfr[4];
    for (int i = 0; i < 2; i++) af[i]  = *(const bf16x8*)&At[(wr + i * 16 + ml) * 32 + qr * 8];
    for (int j = 0; j < 4; j++) bfr[j] = *(const bf16x8*)&Wt[(wc + j * 16 + ml) * 32 + qr * 8];
    for (int i = 0; i < 2; i++)
      for (int j = 0; j < 4; j++)
        acc[i][j] = __builtin_amdgcn_mfma_f32_16x16x32_bf16(af[i], bfr[j], acc[i][j], 0, 0, 0);
    __syncthreads();
  }
  for (int i = 0; i < 2; i++)
    for (int j = 0; j < 4; j++)
      for (int r = 0; r < 4; r++)
        partial[((size_t)blockIdx.y * BB + b0 + wr + i * 16 + qr * 4 + r) * NCLS + wc + j * 16 + ml] =
            acc[i][j][r];
}

__global__ void fc_reduce(const float* __restrict__ partial, const float* __restrict__ fcb,
                          float* __restrict__ out) {
  int i = blockIdx.x * 256 + threadIdx.x;  // B*128
  float s = fcb[i & 127];
  for (int p = 0; p < 16; p++) s += partial[(size_t)p * (BB * NCLS) + i];
  out[i] = s;
}

// ---------------- host ----------------
extern "C" void kernel_launch(void* const* d_in, const int* in_sizes, int n_in,
                              void* d_out, int out_size, void* d_ws, size_t ws_size,
                              hipStream_t stream) {
  const float* x    = (const float*)d_in[0];
  const float* wih0 = (const float*)d_in[1];
  const float* whh0 = (const float*)d_in[2];
  const float* bih0 = (const float*)d_in[3];
  const float* bhh0 = (const float*)d_in[4];
  const float* wih  = (const float*)d_in[5];
  const float* whh  = (const float*)d_in[6];
  const float* bih  = (const float*)d_in[7];
  const float* bhh  = (const float*)d_in[8];
  const float* fcw  = (const float*)d_in[9];
  const float* fcb  = (const float*)d_in[10];
  float* out = (float*)d_out;

  hipFuncSetAttribute((const void*)layer_kernel<2>,
                      hipFuncAttributeMaxDynamicSharedMemorySize, 131072);
  hipFuncSetAttribute((const void*)layer_kernel<16>,
                      hipFuncAttributeMaxDynamicSharedMemorySize, 131072);

  size_t off = 0;
  char* base = (char*)d_ws;
  auto carve = [&](size_t bytes) -> char* {
    char* p = base + off;
    off += (bytes + 255) & ~(size_t)255;
    return p;
  };
  __bf16*   xin   = (__bf16*)carve((size_t)TT * BB * IND * 2);
  __bf16*   Wp    = (__bf16*)carve((size_t)NLAYER * G4 * KP * 2);
  __bf16*   fcwb  = (__bf16*)carve((size_t)NCLS * TT * HH * 2);
  float*    biasb = (float*)carve((size_t)NLAYER * G4 * 4);
  __bf16*   hseqA = (__bf16*)carve((size_t)TT * BB * HH * 2);
  __bf16*   hseqB = (__bf16*)carve((size_t)TT * BB * HH * 2);
  __bf16*   hzero = (__bf16*)carve((size_t)BB * HH * 2);
  float*    part  = (float*)carve((size_t)16 * BB * NCLS * 4);
  unsigned* cnt   = (unsigned*)carve((size_t)NLAYER * 16 * 4);
  unsigned* xslot = (unsigned*)carve((size_t)NLAYER * 8 * 4);

  // prep
  pack_w<<<(NLAYER * G4 * KP) / 256, 256, 0, stream>>>(whh0, wih0, whh, wih, Wp);
  cvt_kernel<<<(NCLS * TT * HH) / 256, 256, 0, stream>>>(fcw, fcwb, NCLS * TT * HH);
  bias_prep<<<(NLAYER * G4) / 256, 256, 0, stream>>>(bih0, bhh0, bih, bhh, biasb);
  xpose<<<(TT * BB * IND) / 256, 256, 0, stream>>>(x, xin);
  zero_bf16<<<(BB * HH) / 256, 256, 0, stream>>>(hzero, BB * HH);
  zero_u32<<<1, 256, 0, stream>>>(cnt, NLAYER * 16 + NLAYER * 8);

  for (int l = 0; l < NLAYER; ++l) {
    const __bf16* xs = (l == 0) ? xin : ((l & 1) ? hseqA : hseqB);
    __bf16* Ho = (l & 1) ? hseqB : hseqA;
    const __bf16* Wl = Wp + (size_t)l * G4 * KP;
    const float* bl = biasb + l * G4;
    unsigned* cl = cnt + l * 16;
    unsigned* xl = xslot + l * 8;
    if (l == 0)
      layer_kernel<2><<<256, 256, 131072, stream>>>(xs, IND, Ho, Wl, bl, hzero, cl, xl);
    else
      layer_kernel<16><<<256, 256, 131072, stream>>>(xs, HH, Ho, Wl, bl, hzero, cl, xl);
  }
  const __bf16* hfinal = hseqB;  // layer 7 writes hseqB
  fc_kernel<<<dim3(16, 16), 256, 0, stream>>>(hfinal, fcwb, part);
  fc_reduce<<<(BB * NCLS) / 256, 256, 0, stream>>>(part, fcb, out);
}

// Round 4
// 13135.622 us; speedup vs baseline: 1.5266x; 1.3513x over previous
//
#include <hip/hip_runtime.h>
#include <hip/hip_bf16.h>

#define BB   1024
#define TT   64
#define IND  64
#define HH   512
#define G4   2048   // 4*H
#define NLAYER 8
#define NCLS 128
#define KP   1024   // packed W k-stride: k<512 = W_hh, k>=512 = W_ih (layer0 64 + pad)

typedef __bf16 bf16x8 __attribute__((ext_vector_type(8)));
typedef float  f32x4  __attribute__((ext_vector_type(4)));

typedef const __attribute__((address_space(1))) void* as1cvp;
typedef __attribute__((address_space(3))) void* as3vp;

__device__ __forceinline__ void gload16(void* lds, const void* g) {
  __builtin_amdgcn_global_load_lds((as1cvp)g, (as3vp)lds, 16, 0, 0);
}

__device__ __forceinline__ float sigmf(float x) { return 1.f / (1.f + __expf(-x)); }
__device__ __forceinline__ float tanhfast(float x) { return 2.f / (1.f + __expf(-2.f * x)) - 1.f; }

// ---------------- prep kernels ----------------
__global__ void cvt_kernel(const float* __restrict__ s, __bf16* __restrict__ d, int n) {
  int i = blockIdx.x * 256 + threadIdx.x;
  if (i < n) d[i] = (__bf16)s[i];
}

__global__ void pack_w(const float* __restrict__ whh0, const float* __restrict__ wih0,
                       const float* __restrict__ whh, const float* __restrict__ wih,
                       __bf16* __restrict__ Wp) {
  int i = blockIdx.x * 256 + threadIdx.x;  // 8*2048*1024
  int k = i & (KP - 1), n = (i >> 10) & 2047, l = i >> 21;
  float v;
  if (k < 512) v = (l == 0) ? whh0[n * 512 + k] : whh[((size_t)(l - 1) * G4 + n) * 512 + k];
  else if (l == 0) v = (k < 512 + IND) ? wih0[n * IND + (k - 512)] : 0.f;
  else v = wih[((size_t)(l - 1) * G4 + n) * 512 + (k - 512)];
  Wp[i] = (__bf16)v;
}

__global__ void bias_prep(const float* __restrict__ bi0, const float* __restrict__ bh0,
                          const float* __restrict__ bi, const float* __restrict__ bh,
                          float* __restrict__ biasb) {
  int i = blockIdx.x * 256 + threadIdx.x;  // 8*2048
  int l = i >> 11, k = i & 2047;
  float v = (l == 0) ? (bi0[k] + bh0[k]) : (bi[(l - 1) * G4 + k] + bh[(l - 1) * G4 + k]);
  biasb[i] = v;
}

__global__ void xpose(const float* __restrict__ x, __bf16* __restrict__ xin) {
  int i = blockIdx.x * 256 + threadIdx.x;  // B*T*64
  int ii = i & 63;
  int t = (i >> 6) & 63;
  int b = i >> 12;
  xin[((size_t)t * BB + b) * IND + ii] = (__bf16)x[i];
}

__global__ void zero_u32(unsigned* __restrict__ p, int n) {
  int i = blockIdx.x * 256 + threadIdx.x;
  if (i < n) p[i] = 0u;
}

// ---------------- persistent fused LSTM layer ----------------
// grid 256 (1 block/CU forced by 128KB LDS), block 256.
// Block identity claimed at runtime from its XCD (s_getreg XCC_ID) -> per-XCD
// static W_ih slice (512KB) stays L2-resident. W_hh tile (128KB) in LDS,
// XOR-swizzled. Cols = 4 gates x 32 j -> cell update register-local; c in regs.
// Step pipeline: [x-part GEMM (spin-independent)] -> [tid0-spin + LDS bcast]
// -> [h A-frag register burst + h-part GEMM] -> activations -> store -> release.
// Counters padded to 256B/bx; only tid0 polls (16 pollers/line, not 1024 waves).
template <int NKX>
__global__ __launch_bounds__(256, 1) void layer_kernel(
    const __bf16* __restrict__ xseq, const int xstr,
    __bf16* __restrict__ Hout,
    const __bf16* __restrict__ Wl,      // this layer's packed W [2048][KP]
    const float* __restrict__ bias,     // [2048]
    unsigned* __restrict__ cnt,         // [16*64] per-bx counters, 256B stride
    unsigned* __restrict__ xslot) {     // [8] per-XCD slot counters
  extern __shared__ __bf16 Wlds[];      // 128KB = 16 slices x (128 rows x 32 k)
  __shared__ int sb[2];
  __shared__ unsigned sv;
  const int tid = threadIdx.x;

  if (tid == 0) {
    unsigned xcc;
    asm volatile("s_getreg_b32 %0, hwreg(HW_REG_XCC_ID)" : "=s"(xcc));
    xcc &= 7u;
    unsigned slot = __hip_atomic_fetch_add(xslot + xcc, 1u, __ATOMIC_RELAXED,
                                           __HIP_MEMORY_SCOPE_AGENT) & 31u;
    sb[0] = (int)(((xcc >> 2) << 3) | (slot >> 2));   // bx 0..15
    sb[1] = (int)(((xcc & 3) << 2) | (slot & 3));     // by 0..15
  }
  __syncthreads();
  const int bx = sb[0], by = sb[1];
  const int b0 = bx << 6, j0 = by << 5;

  const int lane = tid & 63, wv = tid >> 6;
  const int qr = lane >> 4, ml = lane & 15;
  const int wr = (wv >> 1) << 5;   // {0,32} row-half
  const int sub = (wv & 1) << 4;   // {0,16} j-half

  // ---- stage W_hh (k<512) into LDS, swizzled: granule g' = g ^ ((u>>1)&3)
  for (int it = 0; it < 32; ++it) {
    const int p = it * 256 + tid;           // granule 0..8191
    const int kt = p >> 9;                  // k-slice 0..15
    const int q = p & 511;
    const int u = q >> 2;                   // lds row 0..127
    const int g = (q & 3) ^ ((u >> 1) & 3); // source k-quad
    const int n = ((u >> 5) << 9) + j0 + (u & 31);
    gload16(&Wlds[p * 8], Wl + (size_t)n * KP + kt * 32 + g * 8);
  }

  const __bf16* wb[4];
  float bv[4];
  int wsw[4];
#pragma unroll
  for (int g = 0; g < 4; ++g) {
    const int n = g * 512 + j0 + sub + ml;
    wb[g] = Wl + (size_t)n * KP + 512 + qr * 8;   // W_ih (L2-resident)
    bv[g] = bias[n];
    const int u = g * 32 + sub + ml;
    wsw[g] = u * 32 + ((qr ^ ((u >> 1) & 3)) << 3);
  }
  const int rowA0 = b0 + wr + ml;
  const int rowA1 = rowA0 + 16;
  const int rb = b0 + wr + (qr << 2);
  const int jcol = j0 + sub + ml;
  float c8[2][4] = {{0.f, 0.f, 0.f, 0.f}, {0.f, 0.f, 0.f, 0.f}};

  __syncthreads();  // W_hh staged

  for (int t = 0; t < TT; ++t) {
    f32x4 acc[2][4];
#pragma unroll
    for (int g = 0; g < 4; ++g)
#pragma unroll
      for (int r = 0; r < 4; ++r) {
        acc[0][g][r] = bv[g];
        acc[1][g][r] = bv[g];
      }

    // ---- x-part (no dependence on h[t-1]; overlaps producers' work)
    const __bf16* x0 = xseq + ((size_t)t * BB + rowA0) * xstr + qr * 8;
    const __bf16* x1 = xseq + ((size_t)t * BB + rowA1) * xstr + qr * 8;
#pragma unroll
    for (int kt = 0; kt < NKX; ++kt) {
      const bf16x8 af0 = *(const bf16x8*)(x0 + kt * 32);
      const bf16x8 af1 = *(const bf16x8*)(x1 + kt * 32);
#pragma unroll
      for (int g = 0; g < 4; ++g) {
        const bf16x8 wf = *(const bf16x8*)(wb[g] + kt * 32);
        acc[0][g] = __builtin_amdgcn_mfma_f32_16x16x32_bf16(af0, wf, acc[0][g], 0, 0, 0);
        acc[1][g] = __builtin_amdgcn_mfma_f32_16x16x32_bf16(af1, wf, acc[1][g], 0, 0, 0);
      }
    }

    // ---- h-part (skipped at t=0: h==0 contributes nothing)
    if (t > 0) {
      if (tid == 0) {
        const unsigned tgt = (unsigned)(t << 4);
        unsigned v = __hip_atomic_load(cnt + bx * 64, __ATOMIC_RELAXED,
                                       __HIP_MEMORY_SCOPE_AGENT);
        while (v < tgt) {
          __builtin_amdgcn_s_sleep(1);
          v = __hip_atomic_load(cnt + bx * 64, __ATOMIC_RELAXED,
                                __HIP_MEMORY_SCOPE_AGENT);
        }
        sv = v;
      }
      __syncthreads();
      // (sv>>20)==0 at runtime; data-dependence keeps h loads after the spin.
      const __bf16* hp = Hout + (size_t)(t - 1) * BB * HH + (sv >> 20);
      const __bf16* a0 = hp + (size_t)rowA0 * HH + qr * 8;
      const __bf16* a1 = hp + (size_t)rowA1 * HH + qr * 8;
      bf16x8 ah0[16], ah1[16];
#pragma unroll
      for (int kt = 0; kt < 16; ++kt) {
        ah0[kt] = *(const bf16x8*)(a0 + kt * 32);
        ah1[kt] = *(const bf16x8*)(a1 + kt * 32);
      }
#pragma unroll
      for (int kt = 0; kt < 16; ++kt) {
#pragma unroll
        for (int g = 0; g < 4; ++g) {
          const bf16x8 wf = *(const bf16x8*)&Wlds[kt * 4096 + wsw[g]];
          acc[0][g] = __builtin_amdgcn_mfma_f32_16x16x32_bf16(ah0[kt], wf, acc[0][g], 0, 0, 0);
          acc[1][g] = __builtin_amdgcn_mfma_f32_16x16x32_bf16(ah1[kt], wf, acc[1][g], 0, 0, 0);
        }
      }
    }

    // ---- activations + h store
    __bf16* ho = Hout + (size_t)t * BB * HH;
#pragma unroll
    for (int i = 0; i < 2; ++i)
#pragma unroll
      for (int r = 0; r < 4; ++r) {
        const float gi = sigmf(acc[i][0][r]);
        const float gf = sigmf(acc[i][1][r]);
        const float gg = tanhfast(acc[i][2][r]);
        const float go = sigmf(acc[i][3][r]);
        const float cv = gf * c8[i][r] + gi * gg;
        c8[i][r] = cv;
        ho[(size_t)(rb + i * 16 + r) * HH + jcol] = (__bf16)(go * tanhfast(cv));
      }
    if (t < TT - 1) {
      __syncthreads();  // drains vmcnt(0): stores complete before release
      if (tid == 0)
        __hip_atomic_fetch_add(cnt + bx * 64, 1u, __ATOMIC_RELEASE,
                               __HIP_MEMORY_SCOPE_AGENT);
    }
  }
}

// ---------------- FC (bf16 MFMA, K-split) ----------------
__global__ __launch_bounds__(256, 2) void fc_kernel(
    const __bf16* __restrict__ hseq, const __bf16* __restrict__ fcw,
    float* __restrict__ partial) {
  __shared__ __bf16 At[64 * 32];
  __shared__ __bf16 Wt[128 * 32];
  const int tid = threadIdx.x;
  const int b0 = blockIdx.x * 64;
  const int kbase = blockIdx.y * 2048;
  const int lane = tid & 63, wv = tid >> 6;
  const int qr = lane >> 4, ml = lane & 15;
  const int wr = (wv >> 1) * 32, wc = (wv & 1) * 64;
  const int sr = tid >> 2, sk = (tid & 3) * 8;

  f32x4 acc[2][4];
  for (int i = 0; i < 2; i++)
    for (int j = 0; j < 4; j++)
      for (int r = 0; r < 4; r++) acc[i][j][r] = 0.f;

  for (int kt = 0; kt < 64; ++kt) {
    const int k = kbase + kt * 32;
    const int t = k >> 9;
    const int jb = k & 511;
    gload16(&At[tid * 8],        hseq + ((size_t)t * BB + b0 + sr) * HH + jb + sk);
    gload16(&Wt[tid * 8],        fcw + (size_t)sr * (TT * HH) + k + sk);
    gload16(&Wt[2048 + tid * 8], fcw + (size_t)(sr + 64) * (TT * HH) + k + sk);
    __syncthreads();
    bf16x8 af[2], bfr[4];
    for (int i = 0; i < 2; i++) af[i]  = *(const bf16x8*)&At[(wr + i * 16 + ml) * 32 + qr * 8];
    for (int j = 0; j < 4; j++) bfr[j] = *(const bf16x8*)&Wt[(wc + j * 16 + ml) * 32 + qr * 8];
    for (int i = 0; i < 2; i++)
      for (int j = 0; j < 4; j++)
        acc[i][j] = __builtin_amdgcn_mfma_f32_16x16x32_bf16(af[i], bfr[j], acc[i][j], 0, 0, 0);
    __syncthreads();
  }
  for (int i = 0; i < 2; i++)
    for (int j = 0; j < 4; j++)
      for (int r = 0; r < 4; r++)
        partial[((size_t)blockIdx.y * BB + b0 + wr + i * 16 + qr * 4 + r) * NCLS + wc + j * 16 + ml] =
            acc[i][j][r];
}

__global__ void fc_reduce(const float* __restrict__ partial, const float* __restrict__ fcb,
                          float* __restrict__ out) {
  int i = blockIdx.x * 256 + threadIdx.x;  // B*128
  float s = fcb[i & 127];
  for (int p = 0; p < 16; p++) s += partial[(size_t)p * (BB * NCLS) + i];
  out[i] = s;
}

// ---------------- host ----------------
extern "C" void kernel_launch(void* const* d_in, const int* in_sizes, int n_in,
                              void* d_out, int out_size, void* d_ws, size_t ws_size,
                              hipStream_t stream) {
  const float* x    = (const float*)d_in[0];
  const float* wih0 = (const float*)d_in[1];
  const float* whh0 = (const float*)d_in[2];
  const float* bih0 = (const float*)d_in[3];
  const float* bhh0 = (const float*)d_in[4];
  const float* wih  = (const float*)d_in[5];
  const float* whh  = (const float*)d_in[6];
  const float* bih  = (const float*)d_in[7];
  const float* bhh  = (const float*)d_in[8];
  const float* fcw  = (const float*)d_in[9];
  const float* fcb  = (const float*)d_in[10];
  float* out = (float*)d_out;

  hipFuncSetAttribute((const void*)layer_kernel<2>,
                      hipFuncAttributeMaxDynamicSharedMemorySize, 131072);
  hipFuncSetAttribute((const void*)layer_kernel<16>,
                      hipFuncAttributeMaxDynamicSharedMemorySize, 131072);

  size_t off = 0;
  char* base = (char*)d_ws;
  auto carve = [&](size_t bytes) -> char* {
    char* p = base + off;
    off += (bytes + 255) & ~(size_t)255;
    return p;
  };
  __bf16*   xin   = (__bf16*)carve((size_t)TT * BB * IND * 2);
  __bf16*   Wp    = (__bf16*)carve((size_t)NLAYER * G4 * KP * 2);
  __bf16*   fcwb  = (__bf16*)carve((size_t)NCLS * TT * HH * 2);
  float*    biasb = (float*)carve((size_t)NLAYER * G4 * 4);
  __bf16*   hseqA = (__bf16*)carve((size_t)TT * BB * HH * 2);
  __bf16*   hseqB = (__bf16*)carve((size_t)TT * BB * HH * 2);
  float*    part  = (float*)carve((size_t)16 * BB * NCLS * 4);
  unsigned* cnt   = (unsigned*)carve((size_t)NLAYER * 16 * 64 * 4);  // 256B/bx
  unsigned* xslot = (unsigned*)carve((size_t)NLAYER * 8 * 4);

  // prep
  pack_w<<<(NLAYER * G4 * KP) / 256, 256, 0, stream>>>(whh0, wih0, whh, wih, Wp);
  cvt_kernel<<<(NCLS * TT * HH) / 256, 256, 0, stream>>>(fcw, fcwb, NCLS * TT * HH);
  bias_prep<<<(NLAYER * G4) / 256, 256, 0, stream>>>(bih0, bhh0, bih, bhh, biasb);
  xpose<<<(TT * BB * IND) / 256, 256, 0, stream>>>(x, xin);
  zero_u32<<<(NLAYER * 16 * 64 + 255) / 256, 256, 0, stream>>>(cnt, NLAYER * 16 * 64);
  zero_u32<<<1, 256, 0, stream>>>(xslot, NLAYER * 8);

  for (int l = 0; l < NLAYER; ++l) {
    const __bf16* xs = (l == 0) ? xin : ((l & 1) ? hseqA : hseqB);
    __bf16* Ho = (l & 1) ? hseqB : hseqA;
    const __bf16* Wl = Wp + (size_t)l * G4 * KP;
    const float* bl = biasb + l * G4;
    unsigned* cl = cnt + (size_t)l * 16 * 64;
    unsigned* xl = xslot + l * 8;
    if (l == 0)
      layer_kernel<2><<<256, 256, 131072, stream>>>(xs, IND, Ho, Wl, bl, cl, xl);
    else
      layer_kernel<16><<<256, 256, 131072, stream>>>(xs, HH, Ho, Wl, bl, cl, xl);
  }
  const __bf16* hfinal = hseqB;  // layer 7 writes hseqB
  fc_kernel<<<dim3(16, 16), 256, 0, stream>>>(hfinal, fcwb, part);
  fc_reduce<<<(BB * NCLS) / 256, 256, 0, stream>>>(part, fcb, out);
}

// Round 5
// 10295.335 us; speedup vs baseline: 1.9478x; 1.2759x over previous
//
#include <hip/hip_runtime.h>
#include <hip/hip_bf16.h>

#define BB   1024
#define TT   64
#define IND  64
#define HH   512
#define G4   2048   // 4*H
#define NLAYER 8
#define NCLS 128
#define KP   1024   // packed W k-stride: k<512 = W_hh, k>=512 = W_ih (layer0 64 + pad)

typedef __bf16 bf16x8 __attribute__((ext_vector_type(8)));
typedef float  f32x4  __attribute__((ext_vector_type(4)));

typedef const __attribute__((address_space(1))) void* as1cvp;
typedef __attribute__((address_space(3))) void* as3vp;

__device__ __forceinline__ void gload16(void* lds, const void* g) {
  __builtin_amdgcn_global_load_lds((as1cvp)g, (as3vp)lds, 16, 0, 0);
}

__device__ __forceinline__ float sigmf(float x) { return 1.f / (1.f + __expf(-x)); }
__device__ __forceinline__ float tanhfast(float x) { return 2.f / (1.f + __expf(-2.f * x)) - 1.f; }

// ---------------- prep kernels ----------------
__global__ void cvt_kernel(const float* __restrict__ s, __bf16* __restrict__ d, int n) {
  int i = blockIdx.x * 256 + threadIdx.x;
  if (i < n) d[i] = (__bf16)s[i];
}

__global__ void pack_w(const float* __restrict__ whh0, const float* __restrict__ wih0,
                       const float* __restrict__ whh, const float* __restrict__ wih,
                       __bf16* __restrict__ Wp) {
  int i = blockIdx.x * 256 + threadIdx.x;  // 8*2048*1024
  int k = i & (KP - 1), n = (i >> 10) & 2047, l = i >> 21;
  float v;
  if (k < 512) v = (l == 0) ? whh0[n * 512 + k] : whh[((size_t)(l - 1) * G4 + n) * 512 + k];
  else if (l == 0) v = (k < 512 + IND) ? wih0[n * IND + (k - 512)] : 0.f;
  else v = wih[((size_t)(l - 1) * G4 + n) * 512 + (k - 512)];
  Wp[i] = (__bf16)v;
}

__global__ void bias_prep(const float* __restrict__ bi0, const float* __restrict__ bh0,
                          const float* __restrict__ bi, const float* __restrict__ bh,
                          float* __restrict__ biasb) {
  int i = blockIdx.x * 256 + threadIdx.x;  // 8*2048
  int l = i >> 11, k = i & 2047;
  float v = (l == 0) ? (bi0[k] + bh0[k]) : (bi[(l - 1) * G4 + k] + bh[(l - 1) * G4 + k]);
  biasb[i] = v;
}

__global__ void xpose(const float* __restrict__ x, __bf16* __restrict__ xin) {
  int i = blockIdx.x * 256 + threadIdx.x;  // B*T*64
  int ii = i & 63;
  int t = (i >> 6) & 63;
  int b = i >> 12;
  xin[((size_t)t * BB + b) * IND + ii] = (__bf16)x[i];
}

__global__ void zero_u32(unsigned* __restrict__ p, int n) {
  int i = blockIdx.x * 256 + threadIdx.x;
  if (i < n) p[i] = 0u;
}

// ---------------- persistent fused LSTM layer ----------------
// grid 256 (1 block/CU forced by 128KB LDS), block 256.
// Block identity claimed at runtime from its XCD (s_getreg XCC_ID) -> per-XCD
// static W_ih slice stays L2-resident. W_hh tile (128KB) in LDS, XOR-swizzled.
// Cols = 4 gates x 32 j -> cell update register-local; c in regs.
// SYNC (R5): h stored via agent-scope RELAXED ATOMIC STORES (sc0 sc1 ->
// write-through to LLC, no L2 dirty lines), __syncthreads drains vmcnt(0)
// (stores acked at coherence point), then RELAXED atomic add. NO release
// fence anywhere -> no buffer_wbl2 (the R4 killer: full L2 writeback per
// release, 32/XCD/step). Consumer: relaxed poll + data-dependence guard
// (fresh addresses per step; acquire would buffer_inv and evict W_ih).
template <int NKX>
__global__ __launch_bounds__(256, 1) void layer_kernel(
    const __bf16* __restrict__ xseq, const int xstr,
    __bf16* __restrict__ Hout,
    const __bf16* __restrict__ Wl,      // this layer's packed W [2048][KP]
    const float* __restrict__ bias,     // [2048]
    unsigned* __restrict__ cnt,         // [16*64] per-bx counters, 256B stride
    unsigned* __restrict__ xslot) {     // [8] per-XCD slot counters
  extern __shared__ __bf16 Wlds[];      // 128KB = 16 slices x (128 rows x 32 k)
  __shared__ int sb[2];
  __shared__ unsigned sv;
  const int tid = threadIdx.x;

  if (tid == 0) {
    unsigned xcc;
    asm volatile("s_getreg_b32 %0, hwreg(HW_REG_XCC_ID)" : "=s"(xcc));
    xcc &= 7u;
    unsigned slot = __hip_atomic_fetch_add(xslot + xcc, 1u, __ATOMIC_RELAXED,
                                           __HIP_MEMORY_SCOPE_AGENT) & 31u;
    sb[0] = (int)(((xcc >> 2) << 3) | (slot >> 2));   // bx 0..15
    sb[1] = (int)(((xcc & 3) << 2) | (slot & 3));     // by 0..15
  }
  __syncthreads();
  const int bx = sb[0], by = sb[1];
  const int b0 = bx << 6, j0 = by << 5;

  const int lane = tid & 63, wv = tid >> 6;
  const int qr = lane >> 4, ml = lane & 15;
  const int wr = (wv >> 1) << 5;   // {0,32} row-half
  const int sub = (wv & 1) << 4;   // {0,16} j-half

  // ---- stage W_hh (k<512) into LDS, swizzled: granule g' = g ^ ((u>>1)&3)
  for (int it = 0; it < 32; ++it) {
    const int p = it * 256 + tid;           // granule 0..8191
    const int kt = p >> 9;                  // k-slice 0..15
    const int q = p & 511;
    const int u = q >> 2;                   // lds row 0..127
    const int g = (q & 3) ^ ((u >> 1) & 3); // source k-quad
    const int n = ((u >> 5) << 9) + j0 + (u & 31);
    gload16(&Wlds[p * 8], Wl + (size_t)n * KP + kt * 32 + g * 8);
  }

  const __bf16* wb[4];
  float bv[4];
  int wsw[4];
#pragma unroll
  for (int g = 0; g < 4; ++g) {
    const int n = g * 512 + j0 + sub + ml;
    wb[g] = Wl + (size_t)n * KP + 512 + qr * 8;   // W_ih (L2-resident)
    bv[g] = bias[n];
    const int u = g * 32 + sub + ml;
    wsw[g] = u * 32 + ((qr ^ ((u >> 1) & 3)) << 3);
  }
  const int rowA0 = b0 + wr + ml;
  const int rowA1 = rowA0 + 16;
  const int rb = b0 + wr + (qr << 2);
  const int jcol = j0 + sub + ml;
  float c8[2][4] = {{0.f, 0.f, 0.f, 0.f}, {0.f, 0.f, 0.f, 0.f}};

  __syncthreads();  // W_hh staged

  for (int t = 0; t < TT; ++t) {
    f32x4 acc[2][4];
#pragma unroll
    for (int g = 0; g < 4; ++g)
#pragma unroll
      for (int r = 0; r < 4; ++r) {
        acc[0][g][r] = bv[g];
        acc[1][g][r] = bv[g];
      }

    // ---- x-part (no dependence on h[t-1]; overlaps producers' work)
    const __bf16* x0 = xseq + ((size_t)t * BB + rowA0) * xstr + qr * 8;
    const __bf16* x1 = xseq + ((size_t)t * BB + rowA1) * xstr + qr * 8;
#pragma unroll
    for (int kt = 0; kt < NKX; ++kt) {
      const bf16x8 af0 = *(const bf16x8*)(x0 + kt * 32);
      const bf16x8 af1 = *(const bf16x8*)(x1 + kt * 32);
#pragma unroll
      for (int g = 0; g < 4; ++g) {
        const bf16x8 wf = *(const bf16x8*)(wb[g] + kt * 32);
        acc[0][g] = __builtin_amdgcn_mfma_f32_16x16x32_bf16(af0, wf, acc[0][g], 0, 0, 0);
        acc[1][g] = __builtin_amdgcn_mfma_f32_16x16x32_bf16(af1, wf, acc[1][g], 0, 0, 0);
      }
    }

    // ---- h-part (skipped at t=0: h==0 contributes nothing)
    if (t > 0) {
      if (tid == 0) {
        const unsigned tgt = (unsigned)(t << 4);
        unsigned v = __hip_atomic_load(cnt + bx * 64, __ATOMIC_RELAXED,
                                       __HIP_MEMORY_SCOPE_AGENT);
        while (v < tgt) {
          __builtin_amdgcn_s_sleep(1);
          v = __hip_atomic_load(cnt + bx * 64, __ATOMIC_RELAXED,
                                __HIP_MEMORY_SCOPE_AGENT);
        }
        sv = v;
      }
      __syncthreads();
      // (sv>>20)==0 at runtime; data-dependence keeps h loads after the spin.
      const __bf16* hp = Hout + (size_t)(t - 1) * BB * HH + (sv >> 20);
      const __bf16* a0 = hp + (size_t)rowA0 * HH + qr * 8;
      const __bf16* a1 = hp + (size_t)rowA1 * HH + qr * 8;
      bf16x8 ah0[16], ah1[16];
#pragma unroll
      for (int kt = 0; kt < 16; ++kt) {
        ah0[kt] = *(const bf16x8*)(a0 + kt * 32);
        ah1[kt] = *(const bf16x8*)(a1 + kt * 32);
      }
#pragma unroll
      for (int kt = 0; kt < 16; ++kt) {
#pragma unroll
        for (int g = 0; g < 4; ++g) {
          const bf16x8 wf = *(const bf16x8*)&Wlds[kt * 4096 + wsw[g]];
          acc[0][g] = __builtin_amdgcn_mfma_f32_16x16x32_bf16(ah0[kt], wf, acc[0][g], 0, 0, 0);
          acc[1][g] = __builtin_amdgcn_mfma_f32_16x16x32_bf16(ah1[kt], wf, acc[1][g], 0, 0, 0);
        }
      }
    }

    // ---- activations + h store (agent-scope relaxed atomic stores: sc0 sc1,
    // write-through to LLC -> no L2 dirty lines, no wbl2 needed for visibility)
    unsigned short* ho =
        (unsigned short*)(Hout + (size_t)t * BB * HH);
#pragma unroll
    for (int i = 0; i < 2; ++i)
#pragma unroll
      for (int r = 0; r < 4; ++r) {
        const float gi = sigmf(acc[i][0][r]);
        const float gf = sigmf(acc[i][1][r]);
        const float gg = tanhfast(acc[i][2][r]);
        const float go = sigmf(acc[i][3][r]);
        const float cv = gf * c8[i][r] + gi * gg;
        c8[i][r] = cv;
        const __bf16 hv = (__bf16)(go * tanhfast(cv));
        __hip_atomic_store(ho + (size_t)(rb + i * 16 + r) * HH + jcol,
                           __builtin_bit_cast(unsigned short, hv),
                           __ATOMIC_RELAXED, __HIP_MEMORY_SCOPE_AGENT);
      }
    if (t < TT - 1) {
      __syncthreads();  // vmcnt(0): all atomic stores acked at coherence point
      if (tid == 0)
        __hip_atomic_fetch_add(cnt + bx * 64, 1u, __ATOMIC_RELAXED,
                               __HIP_MEMORY_SCOPE_AGENT);
    }
  }
}

// ---------------- FC (bf16 MFMA, K-split) ----------------
__global__ __launch_bounds__(256, 2) void fc_kernel(
    const __bf16* __restrict__ hseq, const __bf16* __restrict__ fcw,
    float* __restrict__ partial) {
  __shared__ __bf16 At[64 * 32];
  __shared__ __bf16 Wt[128 * 32];
  const int tid = threadIdx.x;
  const int b0 = blockIdx.x * 64;
  const int kbase = blockIdx.y * 2048;
  const int lane = tid & 63, wv = tid >> 6;
  const int qr = lane >> 4, ml = lane & 15;
  const int wr = (wv >> 1) * 32, wc = (wv & 1) * 64;
  const int sr = tid >> 2, sk = (tid & 3) * 8;

  f32x4 acc[2][4];
  for (int i = 0; i < 2; i++)
    for (int j = 0; j < 4; j++)
      for (int r = 0; r < 4; r++) acc[i][j][r] = 0.f;

  for (int kt = 0; kt < 64; ++kt) {
    const int k = kbase + kt * 32;
    const int t = k >> 9;
    const int jb = k & 511;
    gload16(&At[tid * 8],        hseq + ((size_t)t * BB + b0 + sr) * HH + jb + sk);
    gload16(&Wt[tid * 8],        fcw + (size_t)sr * (TT * HH) + k + sk);
    gload16(&Wt[2048 + tid * 8], fcw + (size_t)(sr + 64) * (TT * HH) + k + sk);
    __syncthreads();
    bf16x8 af[2], bfr[4];
    for (int i = 0; i < 2; i++) af[i]  = *(const bf16x8*)&At[(wr + i * 16 + ml) * 32 + qr * 8];
    for (int j = 0; j < 4; j++) bfr[j] = *(const bf16x8*)&Wt[(wc + j * 16 + ml) * 32 + qr * 8];
    for (int i = 0; i < 2; i++)
      for (int j = 0; j < 4; j++)
        acc[i][j] = __builtin_amdgcn_mfma_f32_16x16x32_bf16(af[i], bfr[j], acc[i][j], 0, 0, 0);
    __syncthreads();
  }
  for (int i = 0; i < 2; i++)
    for (int j = 0; j < 4; j++)
      for (int r = 0; r < 4; r++)
        partial[((size_t)blockIdx.y * BB + b0 + wr + i * 16 + qr * 4 + r) * NCLS + wc + j * 16 + ml] =
            acc[i][j][r];
}

__global__ void fc_reduce(const float* __restrict__ partial, const float* __restrict__ fcb,
                          float* __restrict__ out) {
  int i = blockIdx.x * 256 + threadIdx.x;  // B*128
  float s = fcb[i & 127];
  for (int p = 0; p < 16; p++) s += partial[(size_t)p * (BB * NCLS) + i];
  out[i] = s;
}

// ---------------- host ----------------
extern "C" void kernel_launch(void* const* d_in, const int* in_sizes, int n_in,
                              void* d_out, int out_size, void* d_ws, size_t ws_size,
                              hipStream_t stream) {
  const float* x    = (const float*)d_in[0];
  const float* wih0 = (const float*)d_in[1];
  const float* whh0 = (const float*)d_in[2];
  const float* bih0 = (const float*)d_in[3];
  const float* bhh0 = (const float*)d_in[4];
  const float* wih  = (const float*)d_in[5];
  const float* whh  = (const float*)d_in[6];
  const float* bih  = (const float*)d_in[7];
  const float* bhh  = (const float*)d_in[8];
  const float* fcw  = (const float*)d_in[9];
  const float* fcb  = (const float*)d_in[10];
  float* out = (float*)d_out;

  hipFuncSetAttribute((const void*)layer_kernel<2>,
                      hipFuncAttributeMaxDynamicSharedMemorySize, 131072);
  hipFuncSetAttribute((const void*)layer_kernel<16>,
                      hipFuncAttributeMaxDynamicSharedMemorySize, 131072);

  size_t off = 0;
  char* base = (char*)d_ws;
  auto carve = [&](size_t bytes) -> char* {
    char* p = base + off;
    off += (bytes + 255) & ~(size_t)255;
    return p;
  };
  __bf16*   xin   = (__bf16*)carve((size_t)TT * BB * IND * 2);
  __bf16*   Wp    = (__bf16*)carve((size_t)NLAYER * G4 * KP * 2);
  __bf16*   fcwb  = (__bf16*)carve((size_t)NCLS * TT * HH * 2);
  float*    biasb = (float*)carve((size_t)NLAYER * G4 * 4);
  __bf16*   hseqA = (__bf16*)carve((size_t)TT * BB * HH * 2);
  __bf16*   hseqB = (__bf16*)carve((size_t)TT * BB * HH * 2);
  float*    part  = (float*)carve((size_t)16 * BB * NCLS * 4);
  unsigned* cnt   = (unsigned*)carve((size_t)NLAYER * 16 * 64 * 4);  // 256B/bx
  unsigned* xslot = (unsigned*)carve((size_t)NLAYER * 8 * 4);

  // prep
  pack_w<<<(NLAYER * G4 * KP) / 256, 256, 0, stream>>>(whh0, wih0, whh, wih, Wp);
  cvt_kernel<<<(NCLS * TT * HH) / 256, 256, 0, stream>>>(fcw, fcwb, NCLS * TT * HH);
  bias_prep<<<(NLAYER * G4) / 256, 256, 0, stream>>>(bih0, bhh0, bih, bhh, biasb);
  xpose<<<(TT * BB * IND) / 256, 256, 0, stream>>>(x, xin);
  zero_u32<<<(NLAYER * 16 * 64 + 255) / 256, 256, 0, stream>>>(cnt, NLAYER * 16 * 64);
  zero_u32<<<1, 256, 0, stream>>>(xslot, NLAYER * 8);

  for (int l = 0; l < NLAYER; ++l) {
    const __bf16* xs = (l == 0) ? xin : ((l & 1) ? hseqA : hseqB);
    __bf16* Ho = (l & 1) ? hseqB : hseqA;
    const __bf16* Wl = Wp + (size_t)l * G4 * KP;
    const float* bl = biasb + l * G4;
    unsigned* cl = cnt + (size_t)l * 16 * 64;
    unsigned* xl = xslot + l * 8;
    if (l == 0)
      layer_kernel<2><<<256, 256, 131072, stream>>>(xs, IND, Ho, Wl, bl, cl, xl);
    else
      layer_kernel<16><<<256, 256, 131072, stream>>>(xs, HH, Ho, Wl, bl, cl, xl);
  }
  const __bf16* hfinal = hseqB;  // layer 7 writes hseqB
  fc_kernel<<<dim3(16, 16), 256, 0, stream>>>(hfinal, fcwb, part);
  fc_reduce<<<(BB * NCLS) / 256, 256, 0, stream>>>(part, fcb, out);
}

// Round 6
// 10208.524 us; speedup vs baseline: 1.9644x; 1.0085x over previous
//
#include <hip/hip_runtime.h>
#include <hip/hip_bf16.h>

#define BB   1024
#define TT   64
#define IND  64
#define HH   512
#define G4   2048   // 4*H
#define NLAYER 8
#define NCLS 128
#define KP   1024   // packed W k-stride: k<512 = W_hh, k>=512 = W_ih (layer0 64 + pad)

typedef __bf16 bf16x8 __attribute__((ext_vector_type(8)));
typedef float  f32x4  __attribute__((ext_vector_type(4)));

typedef const __attribute__((address_space(1))) void* as1cvp;
typedef __attribute__((address_space(3))) void* as3vp;

__device__ __forceinline__ void gload16(void* lds, const void* g) {
  __builtin_amdgcn_global_load_lds((as1cvp)g, (as3vp)lds, 16, 0, 0);
}

__device__ __forceinline__ float sigmf(float x) { return 1.f / (1.f + __expf(-x)); }
__device__ __forceinline__ float tanhfast(float x) { return 2.f / (1.f + __expf(-2.f * x)) - 1.f; }

// L2-scope sync primitives (no sc1 -> executed/served at the XCD's L2;
// sc0 on the load bypasses the CU's L1 so it sees other CUs' L2 updates).
__device__ __forceinline__ unsigned l2_load(const unsigned* p) {
  unsigned v;
  asm volatile("global_load_dword %0, %1, off sc0\n\ts_waitcnt vmcnt(0)"
               : "=v"(v) : "v"(p) : "memory");
  return v;
}
__device__ __forceinline__ void l2_add(unsigned* p, unsigned v) {
  asm volatile("global_atomic_add %0, %1, off" :: "v"(p), "v"(v) : "memory");
}

// ---------------- prep kernels ----------------
__global__ void cvt_kernel(const float* __restrict__ s, __bf16* __restrict__ d, int n) {
  int i = blockIdx.x * 256 + threadIdx.x;
  if (i < n) d[i] = (__bf16)s[i];
}

__global__ void pack_w(const float* __restrict__ whh0, const float* __restrict__ wih0,
                       const float* __restrict__ whh, const float* __restrict__ wih,
                       __bf16* __restrict__ Wp) {
  int i = blockIdx.x * 256 + threadIdx.x;  // 8*2048*1024
  int k = i & (KP - 1), n = (i >> 10) & 2047, l = i >> 21;
  float v;
  if (k < 512) v = (l == 0) ? whh0[n * 512 + k] : whh[((size_t)(l - 1) * G4 + n) * 512 + k];
  else if (l == 0) v = (k < 512 + IND) ? wih0[n * IND + (k - 512)] : 0.f;
  else v = wih[((size_t)(l - 1) * G4 + n) * 512 + (k - 512)];
  Wp[i] = (__bf16)v;
}

__global__ void bias_prep(const float* __restrict__ bi0, const float* __restrict__ bh0,
                          const float* __restrict__ bi, const float* __restrict__ bh,
                          float* __restrict__ biasb) {
  int i = blockIdx.x * 256 + threadIdx.x;  // 8*2048
  int l = i >> 11, k = i & 2047;
  float v = (l == 0) ? (bi0[k] + bh0[k]) : (bi[(l - 1) * G4 + k] + bh[(l - 1) * G4 + k]);
  biasb[i] = v;
}

__global__ void xpose(const float* __restrict__ x, __bf16* __restrict__ xin) {
  int i = blockIdx.x * 256 + threadIdx.x;  // B*T*64
  int ii = i & 63;
  int t = (i >> 6) & 63;
  int b = i >> 12;
  xin[((size_t)t * BB + b) * IND + ii] = (__bf16)x[i];
}

__global__ void zero_u32(unsigned* __restrict__ p, int n) {
  int i = blockIdx.x * 256 + threadIdx.x;
  if (i < n) p[i] = 0u;
}

// ---------------- persistent fused LSTM layer ----------------
// grid 256 (1 block/CU forced by 128KB LDS -> exactly 32 blocks/XCD by
// capacity pigeonhole), block 256.
// R6 mapping: XCD k owns rows bx in {2k,2k+1} x ALL 16 by. Every consumer of
// h[bx] is on the producing XCD -> the whole per-step handshake (h stores,
// counter add, poll, h reload) stays inside one XCD's L2. No cross-die
// latency on the recurrent path. Per-XCD W_ih = 2MB, L2-resident.
// h stores plain (write-back L2, L1 is write-through); release = L2-local
// atomic add (no sc1); poll = sc0 load (bypass L1, read shared L2).
// W_hh tile (128KB) in LDS, XOR-swizzled. c stays in registers.
template <int NKX>
__global__ __launch_bounds__(256, 1) void layer_kernel(
    const __bf16* __restrict__ xseq, const int xstr,
    __bf16* __restrict__ Hout,
    const __bf16* __restrict__ Wl,      // this layer's packed W [2048][KP]
    const float* __restrict__ bias,     // [2048]
    unsigned* __restrict__ cnt,         // [16*64] per-bx counters, 256B stride
    unsigned* __restrict__ xslot) {     // [8] per-XCD slot counters
  extern __shared__ __bf16 Wlds[];      // 128KB = 16 slices x (128 rows x 32 k)
  __shared__ int sb[2];
  __shared__ unsigned sv;
  const int tid = threadIdx.x;

  if (tid == 0) {
    unsigned xcc;
    asm volatile("s_getreg_b32 %0, hwreg(HW_REG_XCC_ID)" : "=s"(xcc));
    xcc &= 7u;
    unsigned slot = __hip_atomic_fetch_add(xslot + xcc, 1u, __ATOMIC_RELAXED,
                                           __HIP_MEMORY_SCOPE_AGENT) & 31u;
    sb[0] = (int)((xcc << 1) | (slot >> 4));  // bx 0..15: XCD-local row pair
    sb[1] = (int)(slot & 15);                 // by 0..15: all j on every XCD
  }
  __syncthreads();
  const int bx = sb[0], by = sb[1];
  const int b0 = bx << 6, j0 = by << 5;

  const int lane = tid & 63, wv = tid >> 6;
  const int qr = lane >> 4, ml = lane & 15;
  const int wr = (wv >> 1) << 5;   // {0,32} row-half
  const int sub = (wv & 1) << 4;   // {0,16} j-half

  // ---- stage W_hh (k<512) into LDS, swizzled: granule g' = g ^ ((u>>1)&3)
  for (int it = 0; it < 32; ++it) {
    const int p = it * 256 + tid;           // granule 0..8191
    const int kt = p >> 9;                  // k-slice 0..15
    const int q = p & 511;
    const int u = q >> 2;                   // lds row 0..127
    const int g = (q & 3) ^ ((u >> 1) & 3); // source k-quad
    const int n = ((u >> 5) << 9) + j0 + (u & 31);
    gload16(&Wlds[p * 8], Wl + (size_t)n * KP + kt * 32 + g * 8);
  }

  const __bf16* wb[4];
  float bv[4];
  int wsw[4];
#pragma unroll
  for (int g = 0; g < 4; ++g) {
    const int n = g * 512 + j0 + sub + ml;
    wb[g] = Wl + (size_t)n * KP + 512 + qr * 8;   // W_ih (L2-resident)
    bv[g] = bias[n];
    const int u = g * 32 + sub + ml;
    wsw[g] = u * 32 + ((qr ^ ((u >> 1) & 3)) << 3);
  }
  const int rowA0 = b0 + wr + ml;
  const int rowA1 = rowA0 + 16;
  const int rb = b0 + wr + (qr << 2);
  const int jcol = j0 + sub + ml;
  float c8[2][4] = {{0.f, 0.f, 0.f, 0.f}, {0.f, 0.f, 0.f, 0.f}};

  __syncthreads();  // W_hh staged

  for (int t = 0; t < TT; ++t) {
    f32x4 acc[2][4];
#pragma unroll
    for (int g = 0; g < 4; ++g)
#pragma unroll
      for (int r = 0; r < 4; ++r) {
        acc[0][g][r] = bv[g];
        acc[1][g][r] = bv[g];
      }

    // ---- x-part (no dependence on h[t-1]; overlaps producers' work)
    const __bf16* x0 = xseq + ((size_t)t * BB + rowA0) * xstr + qr * 8;
    const __bf16* x1 = xseq + ((size_t)t * BB + rowA1) * xstr + qr * 8;
#pragma unroll
    for (int kt = 0; kt < NKX; ++kt) {
      const bf16x8 af0 = *(const bf16x8*)(x0 + kt * 32);
      const bf16x8 af1 = *(const bf16x8*)(x1 + kt * 32);
#pragma unroll
      for (int g = 0; g < 4; ++g) {
        const bf16x8 wf = *(const bf16x8*)(wb[g] + kt * 32);
        acc[0][g] = __builtin_amdgcn_mfma_f32_16x16x32_bf16(af0, wf, acc[0][g], 0, 0, 0);
        acc[1][g] = __builtin_amdgcn_mfma_f32_16x16x32_bf16(af1, wf, acc[1][g], 0, 0, 0);
      }
    }

    // ---- h-part (skipped at t=0: h==0 contributes nothing)
    if (t > 0) {
      if (tid == 0) {
        const unsigned tgt = (unsigned)(t << 4);
        const unsigned* cp = cnt + bx * 64;
        unsigned v = l2_load(cp);
        while (v < tgt) {
          __builtin_amdgcn_s_sleep(1);
          v = l2_load(cp);
        }
        sv = v;
      }
      __syncthreads();
      // (sv>>20)==0 at runtime; data-dependence keeps h loads after the spin.
      const __bf16* hp = Hout + (size_t)(t - 1) * BB * HH + (sv >> 20);
      const __bf16* a0 = hp + (size_t)rowA0 * HH + qr * 8;
      const __bf16* a1 = hp + (size_t)rowA1 * HH + qr * 8;
      bf16x8 ah0[16], ah1[16];
#pragma unroll
      for (int kt = 0; kt < 16; ++kt) {
        ah0[kt] = *(const bf16x8*)(a0 + kt * 32);
        ah1[kt] = *(const bf16x8*)(a1 + kt * 32);
      }
#pragma unroll
      for (int kt = 0; kt < 16; ++kt) {
#pragma unroll
        for (int g = 0; g < 4; ++g) {
          const bf16x8 wf = *(const bf16x8*)&Wlds[kt * 4096 + wsw[g]];
          acc[0][g] = __builtin_amdgcn_mfma_f32_16x16x32_bf16(ah0[kt], wf, acc[0][g], 0, 0, 0);
          acc[1][g] = __builtin_amdgcn_mfma_f32_16x16x32_bf16(ah1[kt], wf, acc[1][g], 0, 0, 0);
        }
      }
    }

    // ---- activations + h store (plain stores: dirty lines in the XCD's L2;
    // consumers are same-XCD, L1s are cold for these fresh addresses)
    __bf16* ho = Hout + (size_t)t * BB * HH;
#pragma unroll
    for (int i = 0; i < 2; ++i)
#pragma unroll
      for (int r = 0; r < 4; ++r) {
        const float gi = sigmf(acc[i][0][r]);
        const float gf = sigmf(acc[i][1][r]);
        const float gg = tanhfast(acc[i][2][r]);
        const float go = sigmf(acc[i][3][r]);
        const float cv = gf * c8[i][r] + gi * gg;
        c8[i][r] = cv;
        ho[(size_t)(rb + i * 16 + r) * HH + jcol] = (__bf16)(go * tanhfast(cv));
      }
    if (t < TT - 1) {
      __syncthreads();  // drains vmcnt(0): stores visible in L2 before release
      if (tid == 0) l2_add(cnt + bx * 64, 1u);
    }
  }
}

// ---------------- FC (bf16 MFMA, K-split) ----------------
__global__ __launch_bounds__(256, 2) void fc_kernel(
    const __bf16* __restrict__ hseq, const __bf16* __restrict__ fcw,
    float* __restrict__ partial) {
  __shared__ __bf16 At[64 * 32];
  __shared__ __bf16 Wt[128 * 32];
  const int tid = threadIdx.x;
  const int b0 = blockIdx.x * 64;
  const int kbase = blockIdx.y * 2048;
  const int lane = tid & 63, wv = tid >> 6;
  const int qr = lane >> 4, ml = lane & 15;
  const int wr = (wv >> 1) * 32, wc = (wv & 1) * 64;
  const int sr = tid >> 2, sk = (tid & 3) * 8;

  f32x4 acc[2][4];
  for (int i = 0; i < 2; i++)
    for (int j = 0; j < 4; j++)
      for (int r = 0; r < 4; r++) acc[i][j][r] = 0.f;

  for (int kt = 0; kt < 64; ++kt) {
    const int k = kbase + kt * 32;
    const int t = k >> 9;
    const int jb = k & 511;
    gload16(&At[tid * 8],        hseq + ((size_t)t * BB + b0 + sr) * HH + jb + sk);
    gload16(&Wt[tid * 8],        fcw + (size_t)sr * (TT * HH) + k + sk);
    gload16(&Wt[2048 + tid * 8], fcw + (size_t)(sr + 64) * (TT * HH) + k + sk);
    __syncthreads();
    bf16x8 af[2], bfr[4];
    for (int i = 0; i < 2; i++) af[i]  = *(const bf16x8*)&At[(wr + i * 16 + ml) * 32 + qr * 8];
    for (int j = 0; j < 4; j++) bfr[j] = *(const bf16x8*)&Wt[(wc + j * 16 + ml) * 32 + qr * 8];
    for (int i = 0; i < 2; i++)
      for (int j = 0; j < 4; j++)
        acc[i][j] = __builtin_amdgcn_mfma_f32_16x16x32_bf16(af[i], bfr[j], acc[i][j], 0, 0, 0);
    __syncthreads();
  }
  for (int i = 0; i < 2; i++)
    for (int j = 0; j < 4; j++)
      for (int r = 0; r < 4; r++)
        partial[((size_t)blockIdx.y * BB + b0 + wr + i * 16 + qr * 4 + r) * NCLS + wc + j * 16 + ml] =
            acc[i][j][r];
}

__global__ void fc_reduce(const float* __restrict__ partial, const float* __restrict__ fcb,
                          float* __restrict__ out) {
  int i = blockIdx.x * 256 + threadIdx.x;  // B*128
  float s = fcb[i & 127];
  for (int p = 0; p < 16; p++) s += partial[(size_t)p * (BB * NCLS) + i];
  out[i] = s;
}

// ---------------- host ----------------
extern "C" void kernel_launch(void* const* d_in, const int* in_sizes, int n_in,
                              void* d_out, int out_size, void* d_ws, size_t ws_size,
                              hipStream_t stream) {
  const float* x    = (const float*)d_in[0];
  const float* wih0 = (const float*)d_in[1];
  const float* whh0 = (const float*)d_in[2];
  const float* bih0 = (const float*)d_in[3];
  const float* bhh0 = (const float*)d_in[4];
  const float* wih  = (const float*)d_in[5];
  const float* whh  = (const float*)d_in[6];
  const float* bih  = (const float*)d_in[7];
  const float* bhh  = (const float*)d_in[8];
  const float* fcw  = (const float*)d_in[9];
  const float* fcb  = (const float*)d_in[10];
  float* out = (float*)d_out;

  hipFuncSetAttribute((const void*)layer_kernel<2>,
                      hipFuncAttributeMaxDynamicSharedMemorySize, 131072);
  hipFuncSetAttribute((const void*)layer_kernel<16>,
                      hipFuncAttributeMaxDynamicSharedMemorySize, 131072);

  size_t off = 0;
  char* base = (char*)d_ws;
  auto carve = [&](size_t bytes) -> char* {
    char* p = base + off;
    off += (bytes + 255) & ~(size_t)255;
    return p;
  };
  __bf16*   xin   = (__bf16*)carve((size_t)TT * BB * IND * 2);
  __bf16*   Wp    = (__bf16*)carve((size_t)NLAYER * G4 * KP * 2);
  __bf16*   fcwb  = (__bf16*)carve((size_t)NCLS * TT * HH * 2);
  float*    biasb = (float*)carve((size_t)NLAYER * G4 * 4);
  __bf16*   hseqA = (__bf16*)carve((size_t)TT * BB * HH * 2);
  __bf16*   hseqB = (__bf16*)carve((size_t)TT * BB * HH * 2);
  float*    part  = (float*)carve((size_t)16 * BB * NCLS * 4);
  unsigned* cnt   = (unsigned*)carve((size_t)NLAYER * 16 * 64 * 4);  // 256B/bx
  unsigned* xslot = (unsigned*)carve((size_t)NLAYER * 8 * 4);

  // prep
  pack_w<<<(NLAYER * G4 * KP) / 256, 256, 0, stream>>>(whh0, wih0, whh, wih, Wp);
  cvt_kernel<<<(NCLS * TT * HH) / 256, 256, 0, stream>>>(fcw, fcwb, NCLS * TT * HH);
  bias_prep<<<(NLAYER * G4) / 256, 256, 0, stream>>>(bih0, bhh0, bih, bhh, biasb);
  xpose<<<(TT * BB * IND) / 256, 256, 0, stream>>>(x, xin);
  zero_u32<<<(NLAYER * 16 * 64 + 255) / 256, 256, 0, stream>>>(cnt, NLAYER * 16 * 64);
  zero_u32<<<1, 256, 0, stream>>>(xslot, NLAYER * 8);

  for (int l = 0; l < NLAYER; ++l) {
    const __bf16* xs = (l == 0) ? xin : ((l & 1) ? hseqA : hseqB);
    __bf16* Ho = (l & 1) ? hseqB : hseqA;
    const __bf16* Wl = Wp + (size_t)l * G4 * KP;
    const float* bl = biasb + l * G4;
    unsigned* cl = cnt + (size_t)l * 16 * 64;
    unsigned* xl = xslot + l * 8;
    if (l == 0)
      layer_kernel<2><<<256, 256, 131072, stream>>>(xs, IND, Ho, Wl, bl, cl, xl);
    else
      layer_kernel<16><<<256, 256, 131072, stream>>>(xs, HH, Ho, Wl, bl, cl, xl);
  }
  const __bf16* hfinal = hseqB;  // layer 7 writes hseqB
  fc_kernel<<<dim3(16, 16), 256, 0, stream>>>(hfinal, fcwb, part);
  fc_reduce<<<(BB * NCLS) / 256, 256, 0, stream>>>(part, fcb, out);
}